// Round 1
// baseline (407.736 us; speedup 1.0000x reference)
//
#include <hip/hip_runtime.h>

#define THREADS 256

__global__ __launch_bounds__(THREADS) void deg_kernel(const int* __restrict__ dst, int E,
                                                      int* __restrict__ deg) {
    int e = blockIdx.x * blockDim.x + threadIdx.x;
    if (e < E) atomicAdd(&deg[dst[e]], 1);
}

__global__ __launch_bounds__(THREADS) void dinv_kernel(const int* __restrict__ deg,
                                                       float* __restrict__ dinv, int N) {
    int i = blockIdx.x * blockDim.x + threadIdx.x;
    if (i < N) dinv[i] = rsqrtf((float)deg[i] + 1.0f);  // +1 self-loop
}

// out = x * dinv[node]^2   (self-loop contribution), float4-vectorized
__global__ __launch_bounds__(THREADS) void selfloop_kernel(const float4* __restrict__ x4,
                                                           const float* __restrict__ dinv,
                                                           float4* __restrict__ out4, int n4) {
    int t = blockIdx.x * blockDim.x + threadIdx.x;
    if (t >= n4) return;
    int node = t >> 4;  // 16 float4 per 64-float row
    float s = dinv[node];
    s *= s;
    float4 v = x4[t];
    v.x *= s; v.y *= s; v.z *= s; v.w *= s;
    out4[t] = v;
}

// one wave per edge (grid-strided); lane = feature
__global__ __launch_bounds__(THREADS) void scatter_kernel(const int* __restrict__ src,
                                                          const int* __restrict__ dst, int E,
                                                          const float* __restrict__ x,
                                                          const float* __restrict__ dinv,
                                                          float* __restrict__ out) {
    int lane = threadIdx.x & 63;
    int wave = (blockIdx.x * blockDim.x + threadIdx.x) >> 6;
    int nwaves = (gridDim.x * blockDim.x) >> 6;
    for (int e = wave; e < E; e += nwaves) {
        int s = src[e];
        int d = dst[e];
        float nrm = dinv[s] * dinv[d];
        float v = x[s * 64 + lane] * nrm;
        atomicAdd(&out[d * 64 + lane], v);
    }
}

// in-place io = io @ W  (W staged in LDS), fused per-feature sum/sumsq stats
__global__ __launch_bounds__(THREADS) void matmul_stats_kernel(float* __restrict__ io,
                                                               const float* __restrict__ W,
                                                               float* __restrict__ stats, int N) {
    __shared__ float Wl[64 * 64];
    int tid = threadIdx.x;
    for (int i = tid; i < 1024; i += THREADS)  // 4096 floats as float4
        ((float4*)Wl)[i] = ((const float4*)W)[i];
    __syncthreads();

    int lane = tid & 63;
    int wave = (blockIdx.x * blockDim.x + tid) >> 6;
    int nwaves = (gridDim.x * blockDim.x) >> 6;
    float sum = 0.f, sq = 0.f;
    for (int i = wave; i < N; i += nwaves) {
        const float4* row4 = (const float4*)(io + (size_t)i * 64);
        float acc = 0.f;
#pragma unroll
        for (int k0 = 0; k0 < 16; ++k0) {
            float4 r = row4[k0];  // wave-uniform address -> broadcast
            acc += r.x * Wl[(k0 * 4 + 0) * 64 + lane];
            acc += r.y * Wl[(k0 * 4 + 1) * 64 + lane];
            acc += r.z * Wl[(k0 * 4 + 2) * 64 + lane];
            acc += r.w * Wl[(k0 * 4 + 3) * 64 + lane];
        }
        io[(size_t)i * 64 + lane] = acc;  // all reads of row i precede this write
        sum += acc;
        sq += acc * acc;
    }
    atomicAdd(&stats[lane], sum);
    atomicAdd(&stats[64 + lane], sq);
}

// y = relu(gamma * (v - mean) * rsqrt(var + eps) + beta), in place, float4
__global__ __launch_bounds__(THREADS) void bn_relu_kernel(float* __restrict__ io,
                                                          const float* __restrict__ stats,
                                                          const float* __restrict__ gamma,
                                                          const float* __restrict__ beta,
                                                          int n4, float invN) {
    int t = blockIdx.x * blockDim.x + threadIdx.x;
    if (t >= n4) return;
    int f0 = (t & 15) * 4;
    float4 v = ((const float4*)io)[t];
    float vv[4] = {v.x, v.y, v.z, v.w};
    float o[4];
#pragma unroll
    for (int j = 0; j < 4; ++j) {
        int f = f0 + j;
        float mean = stats[f] * invN;
        float var = stats[64 + f] * invN - mean * mean;
        float scale = gamma[f] * rsqrtf(var + 1e-5f);
        float shift = beta[f] - mean * scale;
        float y = vv[j] * scale + shift;
        o[j] = y > 0.f ? y : 0.f;
    }
    float4 r = {o[0], o[1], o[2], o[3]};
    ((float4*)io)[t] = r;
}

extern "C" void kernel_launch(void* const* d_in, const int* in_sizes, int n_in,
                              void* d_out, int out_size, void* d_ws, size_t ws_size,
                              hipStream_t stream) {
    const float* x     = (const float*)d_in[0];
    const int*   edges = (const int*)d_in[1];
    const float* W     = (const float*)d_in[2];
    // d_in[3] = b : cancels exactly in training-mode BN (and is zero) -> unused
    const float* gamma = (const float*)d_in[4];
    const float* beta  = (const float*)d_in[5];
    float* out = (float*)d_out;

    const int N = in_sizes[0] / 64;
    const int E = in_sizes[1] / 2;
    const int* src = edges;
    const int* dst = edges + E;

    // ws layout: [0, N*4) deg (int) | [N*4, N*4+512) stats (128 f32) | then dinv (N f32)
    char* ws = (char*)d_ws;
    int*   deg   = (int*)ws;
    float* stats = (float*)(ws + (size_t)N * 4);
    float* dinv  = (float*)(ws + (size_t)N * 4 + 512);

    hipMemsetAsync(ws, 0, (size_t)N * 4 + 512, stream);

    deg_kernel<<<(E + THREADS - 1) / THREADS, THREADS, 0, stream>>>(dst, E, deg);
    dinv_kernel<<<(N + THREADS - 1) / THREADS, THREADS, 0, stream>>>(deg, dinv, N);

    int n4 = N * 16;  // N*64/4
    selfloop_kernel<<<(n4 + THREADS - 1) / THREADS, THREADS, 0, stream>>>(
        (const float4*)x, dinv, (float4*)out, n4);

    scatter_kernel<<<1024, THREADS, 0, stream>>>(src, dst, E, x, dinv, out);

    matmul_stats_kernel<<<512, THREADS, 0, stream>>>(out, W, stats, N);

    bn_relu_kernel<<<(n4 + THREADS - 1) / THREADS, THREADS, 0, stream>>>(
        out, stats, gamma, beta, n4, 1.0f / (float)N);
}

// Round 2
// 340.413 us; speedup vs baseline: 1.1978x; 1.1978x over previous
//
#include <hip/hip_runtime.h>

#define THREADS 256

// ---------------- degree histogram ----------------
__global__ __launch_bounds__(THREADS) void deg_kernel(const int* __restrict__ dst, int E,
                                                      int* __restrict__ deg) {
    int e = blockIdx.x * blockDim.x + threadIdx.x;
    if (e < E) atomicAdd(&deg[dst[e]], 1);
}

// ---------------- 3-phase exclusive scan over deg (N <= 65536) ----------------
__global__ __launch_bounds__(THREADS) void scan1(const int* __restrict__ deg, int N,
                                                 int* __restrict__ bsum) {
    __shared__ int lds[THREADS];
    int t = threadIdx.x, b = blockIdx.x;
    int i = b * THREADS + t;
    lds[t] = (i < N) ? deg[i] : 0;
    __syncthreads();
    for (int off = THREADS / 2; off > 0; off >>= 1) {
        if (t < off) lds[t] += lds[t + off];
        __syncthreads();
    }
    if (t == 0) bsum[b] = lds[0];
}

__global__ __launch_bounds__(THREADS) void scan2(int* __restrict__ bsum, int nb) {
    __shared__ int lds[THREADS];
    int t = threadIdx.x;
    int v = (t < nb) ? bsum[t] : 0;
    lds[t] = v;
    __syncthreads();
    for (int off = 1; off < THREADS; off <<= 1) {
        int u = (t >= off) ? lds[t - off] : 0;
        __syncthreads();
        lds[t] += u;
        __syncthreads();
    }
    if (t < nb) bsum[t] = lds[t] - v;  // exclusive
}

__global__ __launch_bounds__(THREADS) void scan3(const int* __restrict__ deg, int N,
                                                 const int* __restrict__ bsum,
                                                 int* __restrict__ offs, int* __restrict__ cursor,
                                                 float* __restrict__ dinv) {
    __shared__ int lds[THREADS];
    int t = threadIdx.x, b = blockIdx.x;
    int i = b * THREADS + t;
    int v = (i < N) ? deg[i] : 0;
    lds[t] = v;
    __syncthreads();
    for (int off = 1; off < THREADS; off <<= 1) {
        int u = (t >= off) ? lds[t - off] : 0;
        __syncthreads();
        lds[t] += u;
        __syncthreads();
    }
    if (i < N) {
        int excl = bsum[b] + lds[t] - v;
        offs[i] = excl;
        cursor[i] = excl;
        dinv[i] = rsqrtf((float)v + 1.0f);  // +1 self-loop
    }
}

// ---------------- CSR fill (counting sort of src by dst) ----------------
__global__ __launch_bounds__(THREADS) void fill_kernel(const int* __restrict__ src,
                                                       const int* __restrict__ dst, int E,
                                                       int* __restrict__ cursor,
                                                       int* __restrict__ csr) {
    int e = blockIdx.x * blockDim.x + threadIdx.x;
    if (e < E) {
        int pos = atomicAdd(&cursor[dst[e]], 1);
        csr[pos] = src[e];
    }
}

// ---------------- pull aggregation: wave per node, lane per feature ----------------
__global__ __launch_bounds__(THREADS) void gather_kernel(const float* __restrict__ x,
                                                         const int* __restrict__ offs,
                                                         const int* __restrict__ deg,
                                                         const int* __restrict__ csr,
                                                         const float* __restrict__ dinv,
                                                         float* __restrict__ out, int N) {
    int lane = threadIdx.x & 63;
    int node = (blockIdx.x * blockDim.x + threadIdx.x) >> 6;
    if (node >= N) return;
    float dd = dinv[node];
    float acc = dd * x[(size_t)node * 64 + lane];  // self-loop (final *dd gives dd^2)
    int start = offs[node];
    int end = start + deg[node];
    for (int j0 = start; j0 < end; j0 += 64) {
        int nj = end - j0;
        if (nj > 64) nj = 64;
        int idx = (lane < nj) ? csr[j0 + lane] : 0;
        float wv = (lane < nj) ? dinv[idx] : 0.f;
        for (int jj = 0; jj < nj; ++jj) {
            int s = __shfl(idx, jj);
            float w = __shfl(wv, jj);
            acc += w * x[(size_t)s * 64 + lane];
        }
    }
    out[(size_t)node * 64 + lane] = dd * acc;
}

// ---------------- in-place io = io @ W (W in LDS) + per-feature stats ----------------
__global__ __launch_bounds__(THREADS) void matmul_stats_kernel(float* __restrict__ io,
                                                               const float* __restrict__ W,
                                                               float* __restrict__ stats, int N) {
    __shared__ float Wl[64 * 64];
    int tid = threadIdx.x;
    for (int i = tid; i < 1024; i += THREADS)
        ((float4*)Wl)[i] = ((const float4*)W)[i];
    __syncthreads();

    int lane = tid & 63;
    int wave = (blockIdx.x * blockDim.x + tid) >> 6;
    int nwaves = (gridDim.x * blockDim.x) >> 6;
    float sum = 0.f, sq = 0.f;
    for (int i = wave; i < N; i += nwaves) {
        const float4* row4 = (const float4*)(io + (size_t)i * 64);
        float acc = 0.f;
#pragma unroll
        for (int k0 = 0; k0 < 16; ++k0) {
            float4 r = row4[k0];
            acc += r.x * Wl[(k0 * 4 + 0) * 64 + lane];
            acc += r.y * Wl[(k0 * 4 + 1) * 64 + lane];
            acc += r.z * Wl[(k0 * 4 + 2) * 64 + lane];
            acc += r.w * Wl[(k0 * 4 + 3) * 64 + lane];
        }
        io[(size_t)i * 64 + lane] = acc;
        sum += acc;
        sq += acc * acc;
    }
    atomicAdd(&stats[lane], sum);
    atomicAdd(&stats[64 + lane], sq);
}

// ---------------- BN + ReLU in place ----------------
__global__ __launch_bounds__(THREADS) void bn_relu_kernel(float* __restrict__ io,
                                                          const float* __restrict__ stats,
                                                          const float* __restrict__ gamma,
                                                          const float* __restrict__ beta,
                                                          int n4, float invN) {
    int t = blockIdx.x * blockDim.x + threadIdx.x;
    if (t >= n4) return;
    int f0 = (t & 15) * 4;
    float4 v = ((const float4*)io)[t];
    float vv[4] = {v.x, v.y, v.z, v.w};
    float o[4];
#pragma unroll
    for (int j = 0; j < 4; ++j) {
        int f = f0 + j;
        float mean = stats[f] * invN;
        float var = stats[64 + f] * invN - mean * mean;
        float scale = gamma[f] * rsqrtf(var + 1e-5f);
        float shift = beta[f] - mean * scale;
        float y = vv[j] * scale + shift;
        o[j] = y > 0.f ? y : 0.f;
    }
    float4 r = {o[0], o[1], o[2], o[3]};
    ((float4*)io)[t] = r;
}

// ---------------- fallback (R1 push path) kernels ----------------
__global__ __launch_bounds__(THREADS) void dinv_kernel(const int* __restrict__ deg,
                                                       float* __restrict__ dinv, int N) {
    int i = blockIdx.x * blockDim.x + threadIdx.x;
    if (i < N) dinv[i] = rsqrtf((float)deg[i] + 1.0f);
}

__global__ __launch_bounds__(THREADS) void selfloop_kernel(const float4* __restrict__ x4,
                                                           const float* __restrict__ dinv,
                                                           float4* __restrict__ out4, int n4) {
    int t = blockIdx.x * blockDim.x + threadIdx.x;
    if (t >= n4) return;
    int node = t >> 4;
    float s = dinv[node];
    s *= s;
    float4 v = x4[t];
    v.x *= s; v.y *= s; v.z *= s; v.w *= s;
    out4[t] = v;
}

__global__ __launch_bounds__(THREADS) void scatter_kernel(const int* __restrict__ src,
                                                          const int* __restrict__ dst, int E,
                                                          const float* __restrict__ x,
                                                          const float* __restrict__ dinv,
                                                          float* __restrict__ out) {
    int lane = threadIdx.x & 63;
    int wave = (blockIdx.x * blockDim.x + threadIdx.x) >> 6;
    int nwaves = (gridDim.x * blockDim.x) >> 6;
    for (int e = wave; e < E; e += nwaves) {
        int s = src[e];
        int d = dst[e];
        float nrm = dinv[s] * dinv[d];
        atomicAdd(&out[d * 64 + lane], x[s * 64 + lane] * nrm);
    }
}

extern "C" void kernel_launch(void* const* d_in, const int* in_sizes, int n_in,
                              void* d_out, int out_size, void* d_ws, size_t ws_size,
                              hipStream_t stream) {
    const float* x     = (const float*)d_in[0];
    const int*   edges = (const int*)d_in[1];
    const float* W     = (const float*)d_in[2];
    // d_in[3] = b cancels exactly in training-mode BN
    const float* gamma = (const float*)d_in[4];
    const float* beta  = (const float*)d_in[5];
    float* out = (float*)d_out;

    const int N = in_sizes[0] / 64;
    const int E = in_sizes[1] / 2;
    const int* src = edges;
    const int* dst = edges + E;
    const int n4 = N * 16;
    const int nb = (N + THREADS - 1) / THREADS;

    char* ws = (char*)d_ws;
    size_t need = (size_t)16 * N + 512 + (size_t)4 * E + 4 * THREADS;

    if (ws_size >= need && nb <= THREADS) {
        // layout: deg[N] | offs[N] | cursor[N] | dinv[N] | stats[128] | bsum[256] | csr[E]
        int*   deg    = (int*)ws;
        int*   offs   = deg + N;
        int*   cursor = offs + N;
        float* dinv   = (float*)(cursor + N);
        float* stats  = dinv + N;
        int*   bsum   = (int*)(stats + 128);
        int*   csr    = bsum + THREADS;

        hipMemsetAsync(deg, 0, (size_t)4 * N, stream);
        hipMemsetAsync(stats, 0, 512, stream);

        deg_kernel<<<(E + THREADS - 1) / THREADS, THREADS, 0, stream>>>(dst, E, deg);
        scan1<<<nb, THREADS, 0, stream>>>(deg, N, bsum);
        scan2<<<1, THREADS, 0, stream>>>(bsum, nb);
        scan3<<<nb, THREADS, 0, stream>>>(deg, N, bsum, offs, cursor, dinv);
        fill_kernel<<<(E + THREADS - 1) / THREADS, THREADS, 0, stream>>>(src, dst, E, cursor, csr);
        gather_kernel<<<(N * 64 + THREADS - 1) / THREADS, THREADS, 0, stream>>>(
            x, offs, deg, csr, dinv, out, N);
        matmul_stats_kernel<<<1024, THREADS, 0, stream>>>(out, W, stats, N);
        bn_relu_kernel<<<(n4 + THREADS - 1) / THREADS, THREADS, 0, stream>>>(
            out, stats, gamma, beta, n4, 1.0f / (float)N);
    } else {
        // fallback: R1 push path (ws: deg[N] | stats[128] | dinv[N])
        int*   deg   = (int*)ws;
        float* stats = (float*)(ws + (size_t)N * 4);
        float* dinv  = (float*)(ws + (size_t)N * 4 + 512);

        hipMemsetAsync(ws, 0, (size_t)N * 4 + 512, stream);
        deg_kernel<<<(E + THREADS - 1) / THREADS, THREADS, 0, stream>>>(dst, E, deg);
        dinv_kernel<<<(N + THREADS - 1) / THREADS, THREADS, 0, stream>>>(deg, dinv, N);
        selfloop_kernel<<<(n4 + THREADS - 1) / THREADS, THREADS, 0, stream>>>(
            (const float4*)x, dinv, (float4*)out, n4);
        scatter_kernel<<<1024, THREADS, 0, stream>>>(src, dst, E, x, dinv, out);
        matmul_stats_kernel<<<512, THREADS, 0, stream>>>(out, W, stats, N);
        bn_relu_kernel<<<(n4 + THREADS - 1) / THREADS, THREADS, 0, stream>>>(
            out, stats, gamma, beta, n4, 1.0f / (float)N);
    }
}